// Round 3
// baseline (8166.041 us; speedup 1.0000x reference)
//
#include <hip/hip_runtime.h>
#include <math.h>

#define DEV __device__ __forceinline__

constexpr int BATCH = 64;
constexpr int TSTEP = 128;
constexpr int IDIM  = 128;
constexpr int HDIM  = 512;
constexpr int VDIM  = 32;
constexpr int LDEC  = 64;
constexpr int NBLK  = 256;
constexpr int BDIM  = 256;
constexpr int CH    = 60;            // k-quad blocks per LDS chunk (60*4 = 240 k per chunk)
constexpr unsigned MAGIC = 0x1357BD1u;
constexpr unsigned SPIN_LIMIT = 1u << 22;   // ~0.5s; only reached on deadlock

// workspace layout (bytes)
constexpr size_t OFF_BAR  = 0;                                        // u32 barrier slots, 128B spaced
constexpr size_t OFF_SIGT = 1024;                                     // signal^T [T][I][B] 4 MiB
constexpr size_t OFF_HT   = OFF_SIGT + (size_t)TSTEP*IDIM*BATCH*4;    // h^T [par][dir][H][B] 512 KiB
constexpr size_t OFF_XD   = OFF_HT   + (size_t)2*2*HDIM*BATCH*4;      // xdec^T [V][B] 8 KiB
constexpr size_t WS_NEED  = OFF_XD   + (size_t)VDIM*BATCH*4;

DEV void gbar(unsigned* cnt, unsigned* gen, unsigned nb, unsigned* dead) {
  __syncthreads();
  if (threadIdx.x == 0) {
    unsigned g = __hip_atomic_load(gen, __ATOMIC_RELAXED, __HIP_MEMORY_SCOPE_AGENT);
    unsigned a = __hip_atomic_fetch_add(cnt, 1u, __ATOMIC_ACQ_REL, __HIP_MEMORY_SCOPE_AGENT);
    if (a >= nb - 1u) {
      __hip_atomic_store(cnt, 0u, __ATOMIC_RELAXED, __HIP_MEMORY_SCOPE_AGENT);
      __hip_atomic_fetch_add(gen, 1u, __ATOMIC_RELEASE, __HIP_MEMORY_SCOPE_AGENT);
    } else {
      unsigned spins = 0;
      while (__hip_atomic_load(gen, __ATOMIC_RELAXED, __HIP_MEMORY_SCOPE_AGENT) == g) {
        __builtin_amdgcn_s_sleep(1);
        ++spins;
        if ((spins & 255u) == 0u) {        // hang-proofing: only touched while spinning
          if (__hip_atomic_load(dead, __ATOMIC_RELAXED, __HIP_MEMORY_SCOPE_AGENT) != 0u) break;
          if (spins > SPIN_LIMIT) {
            __hip_atomic_store(dead, 1u, __ATOMIC_RELAXED, __HIP_MEMORY_SCOPE_AGENT);
            break;
          }
        }
      }
      (void)__hip_atomic_load(gen, __ATOMIC_ACQUIRE, __HIP_MEMORY_SCOPE_AGENT);
    }
  }
  __syncthreads();
}

// Accumulate one LSTM cell's 4 gate dots for (b, j) across K = KX + HDIM.
// xsrcT: [KX][64] transposed input part; hcur: [HDIM][64] transposed h.
template<int KX>
DEV void cell_accum(float acc[4], const float* __restrict__ xsrcT,
                    const float* __restrict__ hcur,
                    const float* const* wx, const float* const* wh,
                    int b, int tid, float (*Xs)[64][4])
{
  constexpr int KB = (KX + HDIM) / 4;
  for (int kb0 = 0; kb0 < KB; kb0 += CH) {
    const int kbe = (kb0 + CH < KB) ? kb0 + CH : KB;
    const int n = (kbe - kb0) * 64;
    __syncthreads();
    for (int idx = tid; idx < n; idx += BDIM) {
      int bb = idx & 63;
      int kb = kb0 + (idx >> 6);
      int k = kb * 4;
      const float* s = (k < KX) ? (xsrcT + (size_t)k*64 + bb)
                                : (hcur + (size_t)(k - KX)*64 + bb);
      float4 v; v.x = s[0]; v.y = s[64]; v.z = s[128]; v.w = s[192];
      *(float4*)&Xs[kb - kb0][bb][0] = v;
    }
    __syncthreads();
    const int kbxe = (KX/4 < kbe) ? KX/4 : kbe;           // end of x-part
    for (int kb = kb0; kb < kbxe; ++kb) {
      float4 xv = *(const float4*)&Xs[kb - kb0][b][0];
      int k = kb * 4;
      #pragma unroll
      for (int g = 0; g < 4; ++g) {
        float4 w = *(const float4*)(wx[g] + k);
        acc[g] += w.x*xv.x + w.y*xv.y + w.z*xv.z + w.w*xv.w;
      }
    }
    const int kbh0 = (kb0 > KX/4) ? kb0 : KX/4;           // start of h-part
    for (int kb = kbh0; kb < kbe; ++kb) {
      float4 xv = *(const float4*)&Xs[kb - kb0][b][0];
      int k = kb * 4 - KX;
      #pragma unroll
      for (int g = 0; g < 4; ++g) {
        float4 w = *(const float4*)(wh[g] + k);
        acc[g] += w.x*xv.x + w.y*xv.y + w.z*xv.z + w.w*xv.w;
      }
    }
  }
}

__global__ void __launch_bounds__(BDIM)
encdec(const float* __restrict__ signal, const float* __restrict__ tgt,
       const float* __restrict__ eWih, const float* __restrict__ eWhh,
       const float* __restrict__ eBih, const float* __restrict__ eBhh,
       const float* __restrict__ dWih, const float* __restrict__ dWhh,
       const float* __restrict__ dBih, const float* __restrict__ dBhh,
       const float* __restrict__ Wout, const float* __restrict__ bOut,
       float* __restrict__ out,
       unsigned* __restrict__ bar, float* __restrict__ sigT,
       float* __restrict__ hT, float* __restrict__ xdT)
{
  __shared__ float Xs[CH][64][4];
  __shared__ float red[BDIM];
  const int blk = blockIdx.x, tid = threadIdx.x;
  const int d  = blk >> 7;          // 0: forward dir, 1: backward dir
  const int js = blk & 127;         // hidden-slice index (4 hidden units each)
  const int b  = tid & 63;          // batch lane
  const int jj = tid >> 6;          // hidden unit within slice
  const int j  = js * 4 + jj;       // hidden unit [0,512)

  // ---- barrier-state init handshake (ws is 0xAA-poisoned each launch) ----
  unsigned* dead = bar + 224;
  if (blk == 0 && tid == 0) {
    #pragma unroll
    for (int q = 1; q <= 7; ++q)
      __hip_atomic_store(bar + q*32, 0u, __ATOMIC_RELAXED, __HIP_MEMORY_SCOPE_AGENT);
    __hip_atomic_store(bar, MAGIC, __ATOMIC_RELEASE, __HIP_MEMORY_SCOPE_AGENT);
  }
  if (tid == 0) {
    unsigned spins = 0;
    while (__hip_atomic_load(bar, __ATOMIC_RELAXED, __HIP_MEMORY_SCOPE_AGENT) != MAGIC) {
      __builtin_amdgcn_s_sleep(1);
      if (++spins > SPIN_LIMIT) break;   // hang-proof: free-run (garbage) instead of deadlock
    }
    (void)__hip_atomic_load(bar, __ATOMIC_ACQUIRE, __HIP_MEMORY_SCOPE_AGENT);
  }
  __syncthreads();
  unsigned *jc = bar + 32, *jg = bar + 64;                      // joint barrier (256 blocks)
  unsigned *dc = bar + (d ? 160 : 96), *dg = bar + (d ? 192 : 128); // per-dir barrier (128)

  // ---- prologue: transpose signal -> sigT[t][i][b] (coalesced staging later) ----
  {
    const int t = blk & 127, ih = blk >> 7;
    float* tile = (float*)Xs;                     // used as [64][65] (padded)
    for (int idx = tid; idx < 64*64; idx += BDIM) {
      int il = idx & 63, bb = idx >> 6;
      tile[il*65 + bb] = signal[((size_t)bb*TSTEP + t)*IDIM + ih*64 + il];
    }
    __syncthreads();
    for (int idx = tid; idx < 64*64; idx += BDIM) {
      int bb = idx & 63, il = idx >> 6;
      sigT[((size_t)t*IDIM + ih*64 + il)*64 + bb] = tile[il*65 + bb];
    }
  }
  // zero this block's h slice, both parities
  hT[((size_t)(0*2 + d)*HDIM + j)*64 + b] = 0.f;
  hT[((size_t)(1*2 + d)*HDIM + j)*64 + b] = 0.f;
  // decoder step-0 input: relu(target_onehot[:,0,:]) transposed
  if (blk < BATCH && tid < VDIM) {
    float tv = tgt[((size_t)blk*LDEC)*VDIM + tid];
    xdT[tid*64 + blk] = tv > 0.f ? tv : 0.f;
  }
  gbar(jc, jg, NBLK, dead);

  // ---- encoder ----
  const float* wx[4]; const float* wh[4]; float bsum[4];
  #pragma unroll
  for (int g = 0; g < 4; ++g) {
    int r = __builtin_amdgcn_readfirstlane(g*HDIM + j);   // wave-uniform row -> SGPR
    wx[g] = eWih + ((size_t)d*4*HDIM + r)*IDIM;
    wh[g] = eWhh + ((size_t)d*4*HDIM + r)*HDIM;
    bsum[g] = eBih[d*4*HDIM + r] + eBhh[d*4*HDIM + r];
  }
  float c = 0.f;
  for (int t = 0; t < TSTEP; ++t) {
    const int cur = t & 1, nxt = cur ^ 1;
    const int td = d ? (TSTEP - 1 - t) : t;               // backward dir scans reversed
    const float* xsrcT = sigT + (size_t)td*IDIM*64;
    const float* hcur  = hT + ((size_t)(cur*2 + d)*HDIM)*64;
    float acc[4] = {0.f, 0.f, 0.f, 0.f};
    cell_accum<IDIM>(acc, xsrcT, hcur, wx, wh, b, tid, Xs);
    float gi = acc[0]+bsum[0], gf = acc[1]+bsum[1], gg = acc[2]+bsum[2], go = acc[3]+bsum[3];
    float si = 1.f/(1.f+expf(-gi)), sf = 1.f/(1.f+expf(-gf)), so = 1.f/(1.f+expf(-go));
    c = sf*c + si*tanhf(gg);
    hT[((size_t)(nxt*2 + d)*HDIM + j)*64 + b] = so*tanhf(c);
    gbar(dc, dg, 128u, dead);
  }
  gbar(jc, jg, NBLK, dead);

  // ---- decoder ----
  #pragma unroll
  for (int g = 0; g < 4; ++g) {
    int r = __builtin_amdgcn_readfirstlane(g*HDIM + j);
    wx[g] = dWih + ((size_t)d*4*HDIM + r)*VDIM;
    wh[g] = dWhh + ((size_t)d*4*HDIM + r)*HDIM;
    bsum[g] = dBih[d*4*HDIM + r] + dBhh[d*4*HDIM + r];
  }
  for (int s = 0; s < LDEC; ++s) {
    const int cur = s & 1, nxt = cur ^ 1;
    const float* hcur = hT + ((size_t)(cur*2 + d)*HDIM)*64;
    float acc[4] = {0.f, 0.f, 0.f, 0.f};
    cell_accum<VDIM>(acc, xdT, hcur, wx, wh, b, tid, Xs);
    float gi = acc[0]+bsum[0], gf = acc[1]+bsum[1], gg = acc[2]+bsum[2], go = acc[3]+bsum[3];
    float si = 1.f/(1.f+expf(-gi)), sf = 1.f/(1.f+expf(-gf)), so = 1.f/(1.f+expf(-go));
    c = sf*c + si*tanhf(gg);
    hT[((size_t)(nxt*2 + d)*HDIM + j)*64 + b] = so*tanhf(c);
    gbar(jc, jg, NBLK, dead);                             // cells done -> h visible

    if (blk < BATCH) {                                    // logits/argmax/log_softmax, block per batch row
      const int bb = blk, v = tid & 31, kc = tid >> 5;
      const float* hx = hT + ((size_t)nxt*2*HDIM)*64 + bb; // [d][k][b], d-major = concat(hf,hb)
      float part = 0.f;
      for (int i0 = 0; i0 < 128; i0 += 4) {
        int kk = kc*128 + i0;
        const float* hp = hx + (size_t)kk*64;
        float4 w = *(const float4*)(Wout + (size_t)v*(2*HDIM) + kk);
        part += w.x*hp[0] + w.y*hp[64] + w.z*hp[128] + w.w*hp[192];
      }
      red[tid] = part;
      __syncthreads();
      if (tid < VDIM) {
        float lg = red[tid];
        #pragma unroll
        for (int q = 1; q < 8; ++q) lg += red[tid + q*32];
        lg += bOut[tid];
        float m = lg; int mi = tid;                       // argmax, first-index tie rule
        #pragma unroll
        for (int off = 16; off >= 1; off >>= 1) {
          float om = __shfl_xor(m, off, 64);
          int omi  = __shfl_xor(mi, off, 64);
          if (om > m || (om == m && omi < mi)) { m = om; mi = omi; }
        }
        float ex = expf(lg - m), ssum = ex;
        #pragma unroll
        for (int off = 16; off >= 1; off >>= 1) ssum += __shfl_xor(ssum, off, 64);
        out[((size_t)bb*LDEC + s)*VDIM + tid] = lg - m - logf(ssum);
        xdT[tid*64 + bb] = (tid == mi) ? 1.f : 0.f;       // next one-hot input
      }
    }
    gbar(jc, jg, NBLK, dead);                             // one-hot visible for step s+1
  }
}

extern "C" void kernel_launch(void* const* d_in, const int* in_sizes, int n_in,
                              void* d_out, int out_size, void* d_ws, size_t ws_size,
                              hipStream_t stream) {
  if (ws_size < WS_NEED) return;  // insufficient scratch: fail validation loudly
  char* base = (char*)d_ws;
  hipLaunchKernelGGL(encdec, dim3(NBLK), dim3(BDIM), 0, stream,
    (const float*)d_in[0],  (const float*)d_in[1],
    (const float*)d_in[2],  (const float*)d_in[3],
    (const float*)d_in[4],  (const float*)d_in[5],
    (const float*)d_in[6],  (const float*)d_in[7],
    (const float*)d_in[8],  (const float*)d_in[9],
    (const float*)d_in[10], (const float*)d_in[11],
    (float*)d_out,
    (unsigned*)(base + OFF_BAR), (float*)(base + OFF_SIGT),
    (float*)(base + OFF_HT),     (float*)(base + OFF_XD));
}

// Round 4
// 4769.040 us; speedup vs baseline: 1.7123x; 1.7123x over previous
//
#include <hip/hip_runtime.h>
#include <math.h>

#define DEV __device__ __forceinline__
typedef __attribute__((ext_vector_type(4))) float f32x4;

constexpr int BATCH = 64;
constexpr int TSTEP = 128;
constexpr int IDIM  = 128;
constexpr int HDIM  = 512;
constexpr int VDIM  = 32;
constexpr int LDEC  = 64;
constexpr int NBLK  = 256;
constexpr int BDIM  = 256;
constexpr unsigned MAGIC = 0x1357BD1u;
constexpr unsigned SPIN_LIMIT = 1u << 22;   // ~0.5s; only on deadlock

// workspace layout (bytes)
constexpr size_t OFF_BAR  = 0;                                        // u32 barrier slots, 128B spaced
constexpr size_t OFF_SIGT = 1024;                                     // signal^T [T][I][B] 4 MiB (plain, immutable)
constexpr size_t OFF_HT   = OFF_SIGT + (size_t)TSTEP*IDIM*BATCH*4;    // h^T [par][dir][H][B] (sc1 only)
constexpr size_t OFF_XD   = OFF_HT   + (size_t)2*2*HDIM*BATCH*4;      // xdec^T [V][B] (sc1 only)
constexpr size_t WS_NEED  = OFF_XD   + (size_t)VDIM*BATCH*4;

// ---- coherent (agent/L3) access helpers: bypass L2, keep it warm ----
DEV float ald(const float* p){ return __hip_atomic_load(p, __ATOMIC_RELAXED, __HIP_MEMORY_SCOPE_AGENT); }
DEV void  ast(float* p, float v){ __hip_atomic_store(p, v, __ATOMIC_RELAXED, __HIP_MEMORY_SCOPE_AGENT); }
DEV void  wait_vm0(){ asm volatile("s_waitcnt vmcnt(0)" ::: "memory"); }
DEV f32x4 gl4_sc1(const float* p){ f32x4 r; asm volatile("global_load_dwordx4 %0, %1, off sc1" : "=v"(r) : "v"(p)); return r; }
DEV f32x4 gl4_pln(const float* p){ f32x4 r; asm volatile("global_load_dwordx4 %0, %1, off"     : "=v"(r) : "v"(p)); return r; }
DEV float gl1_sc1(const float* p){ float r; asm volatile("global_load_dword %0, %1, off sc1"   : "=v"(r) : "v"(p)); return r; }

// legacy barrier WITH cache fences — prologue only (publishes plain sigT stores)
DEV void gbar_full(unsigned* cnt, unsigned* gen, unsigned nb, unsigned* dead) {
  __syncthreads();
  if (threadIdx.x == 0) {
    unsigned g = __hip_atomic_load(gen, __ATOMIC_RELAXED, __HIP_MEMORY_SCOPE_AGENT);
    unsigned a = __hip_atomic_fetch_add(cnt, 1u, __ATOMIC_ACQ_REL, __HIP_MEMORY_SCOPE_AGENT);
    if (a >= nb - 1u) {
      __hip_atomic_store(cnt, 0u, __ATOMIC_RELAXED, __HIP_MEMORY_SCOPE_AGENT);
      __hip_atomic_fetch_add(gen, 1u, __ATOMIC_RELEASE, __HIP_MEMORY_SCOPE_AGENT);
    } else {
      unsigned spins = 0;
      while (__hip_atomic_load(gen, __ATOMIC_RELAXED, __HIP_MEMORY_SCOPE_AGENT) == g) {
        __builtin_amdgcn_s_sleep(1);
        if ((++spins & 255u) == 0u) {
          if (__hip_atomic_load(dead, __ATOMIC_RELAXED, __HIP_MEMORY_SCOPE_AGENT) != 0u) break;
          if (spins > SPIN_LIMIT) { __hip_atomic_store(dead, 1u, __ATOMIC_RELAXED, __HIP_MEMORY_SCOPE_AGENT); break; }
        }
      }
      (void)__hip_atomic_load(gen, __ATOMIC_ACQUIRE, __HIP_MEMORY_SCOPE_AGENT);
    }
  }
  __syncthreads();
}

// steady-state barrier: NO cache fences (all shared data goes through L3 via sc1)
DEV void fastbar(unsigned* cnt, unsigned* gen, unsigned nb, unsigned* dead) {
  wait_vm0();                       // this wave's sc1 stores complete at L3
  __syncthreads();                  // all waves of block (each drains vmcnt)
  if (threadIdx.x == 0) {
    unsigned g = __hip_atomic_load(gen, __ATOMIC_RELAXED, __HIP_MEMORY_SCOPE_AGENT);
    unsigned a = __hip_atomic_fetch_add(cnt, 1u, __ATOMIC_RELAXED, __HIP_MEMORY_SCOPE_AGENT);
    if (a >= nb - 1u) {
      __hip_atomic_store(cnt, 0u, __ATOMIC_RELAXED, __HIP_MEMORY_SCOPE_AGENT);
      __hip_atomic_fetch_add(gen, 1u, __ATOMIC_RELAXED, __HIP_MEMORY_SCOPE_AGENT);
    } else {
      unsigned spins = 0;
      while (__hip_atomic_load(gen, __ATOMIC_RELAXED, __HIP_MEMORY_SCOPE_AGENT) == g) {
        __builtin_amdgcn_s_sleep(1);
        if ((++spins & 255u) == 0u) {
          if (__hip_atomic_load(dead, __ATOMIC_RELAXED, __HIP_MEMORY_SCOPE_AGENT) != 0u) break;
          if (spins > SPIN_LIMIT) { __hip_atomic_store(dead, 1u, __ATOMIC_RELAXED, __HIP_MEMORY_SCOPE_AGENT); break; }
        }
      }
    }
  }
  __syncthreads();
}

// One LSTM cell step: K = KX (x part) + 512 (h part), chunked through LDS double-buffer.
// Chunks of 64 k (x remainder chunk of 32 for KX=32). Staging: asm global loads
// (sc1 for h and, if XSC1, for x) issued after the chunk sync -> fly under compute.
template<int KX, bool XSC1>
DEV void cell_step(float acc[4], const float* __restrict__ xsrc,
                   const float* __restrict__ hcur,
                   const float* const* wx, const float* const* wh,
                   int b, int tid, float* __restrict__ buf)
{
  constexpr int  NXC = KX / 64;             // full 64-k x chunks (2 enc, 0 dec)
  constexpr bool XR  = (KX % 64) != 0;      // 32-k x chunk (dec)
  constexpr int  NC  = NXC + (XR ? 1 : 0) + HDIM / 64;
  f32x4 r[4];

  auto issue = [&](int c) {
    if (c < NXC) {
      const float* s = xsrc + (size_t)c*4096 + tid*4;
      #pragma unroll
      for (int q = 0; q < 4; ++q) r[q] = XSC1 ? gl4_sc1(s + q*1024) : gl4_pln(s + q*1024);
    } else if (XR && c == NXC) {
      const float* s = xsrc + tid*4;
      #pragma unroll
      for (int q = 0; q < 2; ++q) r[q] = XSC1 ? gl4_sc1(s + q*1024) : gl4_pln(s + q*1024);
    } else {
      const int ch = c - NXC - (XR ? 1 : 0);
      const float* s = hcur + (size_t)ch*4096 + tid*4;
      #pragma unroll
      for (int q = 0; q < 4; ++q) r[q] = gl4_sc1(s + q*1024);
    }
  };

  issue(0);
  for (int c = 0; c < NC; ++c) {
    wait_vm0();                                    // chunk-c loads landed
    float* dst = buf + (c & 1)*4096;
    const bool small = (XR && c == NXC);
    *(f32x4*)(dst + tid*4)        = r[0];
    *(f32x4*)(dst + tid*4 + 1024) = r[1];
    if (!small) {
      *(f32x4*)(dst + tid*4 + 2048) = r[2];
      *(f32x4*)(dst + tid*4 + 3072) = r[3];
    }
    __syncthreads();                               // publish buf[c&1]
    if (c + 1 < NC) issue(c + 1);                  // prefetch flies under compute
    const float *g0, *g1, *g2, *g3;
    if (c < NXC)            { g0=wx[0]+c*64; g1=wx[1]+c*64; g2=wx[2]+c*64; g3=wx[3]+c*64; }
    else if (XR && c==NXC)  { g0=wx[0];      g1=wx[1];      g2=wx[2];      g3=wx[3]; }
    else { const int ch=c-NXC-(XR?1:0); g0=wh[0]+ch*64; g1=wh[1]+ch*64; g2=wh[2]+ch*64; g3=wh[3]+ch*64; }
    const float* bs = dst + b;
    if (!small) {
      #pragma unroll
      for (int kk = 0; kk < 64; ++kk) {
        float xv = bs[kk*64];
        acc[0] += g0[kk]*xv; acc[1] += g1[kk]*xv; acc[2] += g2[kk]*xv; acc[3] += g3[kk]*xv;
      }
    } else {
      #pragma unroll
      for (int kk = 0; kk < 32; ++kk) {
        float xv = bs[kk*64];
        acc[0] += g0[kk]*xv; acc[1] += g1[kk]*xv; acc[2] += g2[kk]*xv; acc[3] += g3[kk]*xv;
      }
    }
  }
}

__global__ void __launch_bounds__(BDIM)
encdec(const float* __restrict__ signal, const float* __restrict__ tgt,
       const float* __restrict__ eWih, const float* __restrict__ eWhh,
       const float* __restrict__ eBih, const float* __restrict__ eBhh,
       const float* __restrict__ dWih, const float* __restrict__ dWhh,
       const float* __restrict__ dBih, const float* __restrict__ dBhh,
       const float* __restrict__ Wout, const float* __restrict__ bOut,
       float* __restrict__ out,
       unsigned* __restrict__ bar, float* __restrict__ sigT,
       float* __restrict__ hT, float* __restrict__ xdT)
{
  __shared__ __align__(16) float buf[2*4096];      // 32 KiB chunk double-buffer
  __shared__ float red[BDIM];
  const int blk = blockIdx.x, tid = threadIdx.x;
  const int d  = blk >> 7;
  const int js = blk & 127;
  const int b  = tid & 63;
  const int jj = tid >> 6;
  const int j  = js * 4 + jj;

  unsigned* dead = bar + 224;
  if (blk == 0 && tid == 0) {
    #pragma unroll
    for (int q = 1; q <= 7; ++q)
      __hip_atomic_store(bar + q*32, 0u, __ATOMIC_RELAXED, __HIP_MEMORY_SCOPE_AGENT);
    __hip_atomic_store(bar, MAGIC, __ATOMIC_RELEASE, __HIP_MEMORY_SCOPE_AGENT);
  }
  if (tid == 0) {
    unsigned spins = 0;
    while (__hip_atomic_load(bar, __ATOMIC_RELAXED, __HIP_MEMORY_SCOPE_AGENT) != MAGIC) {
      __builtin_amdgcn_s_sleep(1);
      if (++spins > SPIN_LIMIT) break;
    }
    (void)__hip_atomic_load(bar, __ATOMIC_ACQUIRE, __HIP_MEMORY_SCOPE_AGENT);
  }
  __syncthreads();
  unsigned *jc = bar + 32, *jg = bar + 64;
  unsigned *dc = bar + (d ? 160 : 96), *dg = bar + (d ? 192 : 128);

  // ---- prologue: transpose signal -> sigT[t][i][b] (plain; published by gbar_full) ----
  {
    const int t = blk & 127, ih = blk >> 7;
    float* tile = buf;                               // [64][65] padded, 16.6 KiB
    for (int idx = tid; idx < 64*64; idx += BDIM) {
      int il = idx & 63, bb = idx >> 6;
      tile[il*65 + bb] = signal[((size_t)bb*TSTEP + t)*IDIM + ih*64 + il];
    }
    __syncthreads();
    for (int idx = tid; idx < 64*64; idx += BDIM) {
      int bb = idx & 63, il = idx >> 6;
      sigT[((size_t)t*IDIM + ih*64 + il)*64 + bb] = tile[il*65 + bb];
    }
  }
  // hT / xdT live exclusively in L3 (sc1) — init with agent stores so no L2 copies exist
  ast(&hT[((size_t)(0*2 + d)*HDIM + j)*64 + b], 0.f);
  ast(&hT[((size_t)(1*2 + d)*HDIM + j)*64 + b], 0.f);
  if (blk < BATCH && tid < VDIM) {
    float tv = tgt[((size_t)blk*LDEC)*VDIM + tid];
    ast(&xdT[tid*64 + blk], tv > 0.f ? tv : 0.f);
  }
  gbar_full(jc, jg, NBLK, dead);                     // the ONLY fence barrier

  // ---- encoder ----
  const float* wx[4]; const float* wh[4]; float bsum[4];
  #pragma unroll
  for (int g = 0; g < 4; ++g) {
    int r = __builtin_amdgcn_readfirstlane(g*HDIM + j);
    wx[g] = eWih + ((size_t)d*4*HDIM + r)*IDIM;
    wh[g] = eWhh + ((size_t)d*4*HDIM + r)*HDIM;
    bsum[g] = eBih[d*4*HDIM + r] + eBhh[d*4*HDIM + r];
  }
  float c = 0.f;
  for (int t = 0; t < TSTEP; ++t) {
    const int cur = t & 1, nxt = cur ^ 1;
    const int td = d ? (TSTEP - 1 - t) : t;
    float acc[4] = {0.f, 0.f, 0.f, 0.f};
    cell_step<IDIM, false>(acc, sigT + (size_t)td*IDIM*64,
                           hT + ((size_t)(cur*2 + d)*HDIM)*64, wx, wh, b, tid, buf);
    float gi = acc[0]+bsum[0], gf = acc[1]+bsum[1], gg = acc[2]+bsum[2], go = acc[3]+bsum[3];
    float si = 1.f/(1.f+expf(-gi)), sf = 1.f/(1.f+expf(-gf)), so = 1.f/(1.f+expf(-go));
    c = sf*c + si*tanhf(gg);
    ast(&hT[((size_t)(nxt*2 + d)*HDIM + j)*64 + b], so*tanhf(c));
    fastbar(dc, dg, 128u, dead);
  }
  fastbar(jc, jg, NBLK, dead);

  // ---- decoder ----
  #pragma unroll
  for (int g = 0; g < 4; ++g) {
    int r = __builtin_amdgcn_readfirstlane(g*HDIM + j);
    wx[g] = dWih + ((size_t)d*4*HDIM + r)*VDIM;
    wh[g] = dWhh + ((size_t)d*4*HDIM + r)*HDIM;
    bsum[g] = dBih[d*4*HDIM + r] + dBhh[d*4*HDIM + r];
  }
  for (int s = 0; s < LDEC; ++s) {
    const int cur = s & 1, nxt = cur ^ 1;
    float acc[4] = {0.f, 0.f, 0.f, 0.f};
    cell_step<VDIM, true>(acc, xdT, hT + ((size_t)(cur*2 + d)*HDIM)*64, wx, wh, b, tid, buf);
    float gi = acc[0]+bsum[0], gf = acc[1]+bsum[1], gg = acc[2]+bsum[2], go = acc[3]+bsum[3];
    float si = 1.f/(1.f+expf(-gi)), sf = 1.f/(1.f+expf(-gf)), so = 1.f/(1.f+expf(-go));
    c = sf*c + si*tanhf(gg);
    ast(&hT[((size_t)(nxt*2 + d)*HDIM + j)*64 + b], so*tanhf(c));
    fastbar(jc, jg, NBLK, dead);                     // h visible

    if (blk < BATCH) {                               // logits/argmax/log_softmax
      const int bb = blk, v = tid & 31, kc = tid >> 5;
      const float* hx = hT + (size_t)nxt*2*HDIM*64 + bb;   // [d][k][b] d-major = concat(hf,hb)
      float part = 0.f;
      float rr[32];
      for (int w = 0; w < 4; ++w) {                  // windows of 32 in-flight sc1 loads
        #pragma unroll
        for (int i = 0; i < 32; ++i)
          rr[i] = gl1_sc1(hx + (size_t)(kc*128 + w*32 + i)*64);
        wait_vm0();
        #pragma unroll
        for (int i = 0; i < 32; ++i)
          part += Wout[(size_t)v*(2*HDIM) + kc*128 + w*32 + i] * rr[i];
      }
      red[tid] = part;
      __syncthreads();
      if (tid < VDIM) {
        float lg = red[tid];
        #pragma unroll
        for (int q = 1; q < 8; ++q) lg += red[tid + q*32];
        lg += bOut[tid];
        float m = lg; int mi = tid;                  // argmax, first-index tie rule
        #pragma unroll
        for (int off = 16; off >= 1; off >>= 1) {
          float om = __shfl_xor(m, off, 64);
          int omi  = __shfl_xor(mi, off, 64);
          if (om > m || (om == m && omi < mi)) { m = om; mi = omi; }
        }
        float ex = expf(lg - m), ssum = ex;
        #pragma unroll
        for (int off = 16; off >= 1; off >>= 1) ssum += __shfl_xor(ssum, off, 64);
        out[((size_t)bb*LDEC + s)*VDIM + tid] = lg - m - logf(ssum);
        ast(&xdT[tid*64 + bb], (tid == mi) ? 1.f : 0.f);
      }
    }
    fastbar(jc, jg, NBLK, dead);                     // one-hot visible
  }
}

extern "C" void kernel_launch(void* const* d_in, const int* in_sizes, int n_in,
                              void* d_out, int out_size, void* d_ws, size_t ws_size,
                              hipStream_t stream) {
  if (ws_size < WS_NEED) return;
  char* base = (char*)d_ws;
  hipLaunchKernelGGL(encdec, dim3(NBLK), dim3(BDIM), 0, stream,
    (const float*)d_in[0],  (const float*)d_in[1],
    (const float*)d_in[2],  (const float*)d_in[3],
    (const float*)d_in[4],  (const float*)d_in[5],
    (const float*)d_in[6],  (const float*)d_in[7],
    (const float*)d_in[8],  (const float*)d_in[9],
    (const float*)d_in[10], (const float*)d_in[11],
    (float*)d_out,
    (unsigned*)(base + OFF_BAR), (float*)(base + OFF_SIGT),
    (float*)(base + OFF_HT),     (float*)(base + OFF_XD));
}